// Round 1
// baseline (147.463 us; speedup 1.0000x reference)
//
#include <hip/hip_runtime.h>
#include <math.h>

#define B_ 2
#define N_ 2048
#define H_ 16

constexpr int QB      = 256;          // queries per block
constexpr int KSPLIT  = 4;            // threads per query (key-dim split)
constexpr int THREADS = QB * KSPLIT;  // 1024
constexpr int KCHUNK  = N_ / KSPLIT;  // 512

__global__ __launch_bounds__(THREADS, 1)
void g2attn_kernel(const float* __restrict__ o,
                   const float* __restrict__ mix,
                   const float* __restrict__ alpha,
                   const float* __restrict__ beta,
                   float* __restrict__ out)
{
    // All keys for this (b,h): 2048 rows x 8 floats = 64 KiB
    __shared__ float skv[N_][8];

    const int bh = blockIdx.y;            // 0..31
    const int b  = bh >> 4;
    const int h  = bh & (H_ - 1);
    const int n0 = blockIdx.x * QB;

    const float* obase = o + ((size_t)b * N_ * (H_ * 8)) + h * 8;

    // cooperative stage: N_ rows x 2 float4
    for (int i = threadIdx.x; i < N_ * 2; i += THREADS) {
        const int row = i >> 1, half = i & 1;
        const float4 v = *(const float4*)(obase + (size_t)row * (H_ * 8) + half * 4);
        *(float4*)&skv[row][half * 4] = v;
    }
    __syncthreads();

    const int qi   = threadIdx.x & (QB - 1);
    const int ks   = threadIdx.x / QB;     // 0..3
    const int qrow = n0 + qi;

    // my query (real + 7 imag) into registers BEFORE skv gets reused
    const float4 qA = *(const float4*)&skv[qrow][0];
    const float4 qB = *(const float4*)&skv[qrow][4];
    const float realv = qA.x;
    const float q1 = qA.y, q2 = qA.z, q3 = qA.w;
    const float q4 = qB.x, q5 = qB.y, q6 = qB.z, q7 = qB.w;

    // head constants: w_k = softmax(mix[h])[0]; fold scale & log2(e)
    const float m0 = mix[h * 2 + 0], m1 = mix[h * 2 + 1];
    const float e0 = __expf(m0), e1 = __expf(m1);
    const float wk = e0 / (e0 + e1);
    const float c2 = wk * (1.44269504088896340736f / 2.64575131106459059050f); // log2e/sqrt(7)

    // no-max softmax accumulation (scores bounded -> fp32 safe)
    float l = 0.f, a1 = 0.f, a2 = 0.f, a3 = 0.f, a4 = 0.f, a5 = 0.f, a6 = 0.f, a7 = 0.f;
    const int t0 = ks * KCHUNK;
    #pragma unroll 4
    for (int t = t0; t < t0 + KCHUNK; ++t) {
        const float4 kA = *(const float4*)&skv[t][0];
        const float4 kB = *(const float4*)&skv[t][4];
        float s = q1 * kA.y;
        s = fmaf(q2, kA.z, s); s = fmaf(q3, kA.w, s); s = fmaf(q4, kB.x, s);
        s = fmaf(q5, kB.y, s); s = fmaf(q6, kB.z, s); s = fmaf(q7, kB.w, s);
        const float p = exp2f(s * c2);
        l += p;
        a1 = fmaf(p, kA.y, a1); a2 = fmaf(p, kA.z, a2); a3 = fmaf(p, kA.w, a3);
        a4 = fmaf(p, kB.x, a4); a5 = fmaf(p, kB.y, a5); a6 = fmaf(p, kB.z, a6);
        a7 = fmaf(p, kB.w, a7);
    }

    // merge KSPLIT partials through LDS (reuse skv — all reads done)
    __syncthreads();
    float* part = &skv[0][0];
    if (ks > 0) {
        float* p = part + ((size_t)(ks - 1) * QB + qi) * 8;
        p[0] = l;  p[1] = a1; p[2] = a2; p[3] = a3;
        p[4] = a4; p[5] = a5; p[6] = a6; p[7] = a7;
    }
    __syncthreads();

    if (ks == 0) {
        #pragma unroll
        for (int s2 = 0; s2 < KSPLIT - 1; ++s2) {
            const float* p = part + ((size_t)s2 * QB + qi) * 8;
            l  += p[0]; a1 += p[1]; a2 += p[2]; a3 += p[3];
            a4 += p[4]; a5 += p[5]; a6 += p[6]; a7 += p[7];
        }
        const float invl = 1.0f / l;
        // y_v == k_pooled (k ≡ v)
        float ya[7] = { a1 * invl, a2 * invl, a3 * invl, a4 * invl,
                        a5 * invl, a6 * invl, a7 * invl };
        float qa[7] = { q1, q2, q3, q4, q5, q6, q7 };

        // y_x = oct_cross(q, y_v) via Fano triples
        constexpr int TR[7][3] = {{0,1,2},{0,3,4},{0,6,5},{1,3,5},{1,4,6},{2,3,6},{2,5,4}};
        float xa[7] = {0.f, 0.f, 0.f, 0.f, 0.f, 0.f, 0.f};
        #pragma unroll
        for (int t = 0; t < 7; ++t) {
            const int i = TR[t][0], j = TR[t][1], k = TR[t][2];
            xa[k] += qa[i] * ya[j] - qa[j] * ya[i];
            xa[i] += qa[j] * ya[k] - qa[k] * ya[j];
            xa[j] += qa[k] * ya[i] - qa[i] * ya[k];
        }

        const float sa = 1.0f / (1.0f + __expf(-alpha[h]));
        const float tb = tanhf(beta[h]);

        float im[7];
        float nsq = realv * realv;
        #pragma unroll
        for (int d = 0; d < 7; ++d) {
            im[d] = sa * ya[d] + tb * xa[d];
            nsq = fmaf(im[d], im[d], nsq);
        }
        const float inv = 1.0f / fmaxf(sqrtf(nsq), 1e-12f);

        float4 oA = { realv * inv, im[0] * inv, im[1] * inv, im[2] * inv };
        float4 oB = { im[3] * inv, im[4] * inv, im[5] * inv, im[6] * inv };
        float* dst = out + ((size_t)(b * N_ + qrow) * H_ + h) * 8;
        *(float4*)(dst)     = oA;
        *(float4*)(dst + 4) = oB;
    }
}

extern "C" void kernel_launch(void* const* d_in, const int* in_sizes, int n_in,
                              void* d_out, int out_size, void* d_ws, size_t ws_size,
                              hipStream_t stream) {
    const float* o     = (const float*)d_in[0];
    const float* mix   = (const float*)d_in[1];
    const float* alpha = (const float*)d_in[2];
    const float* beta  = (const float*)d_in[3];
    float* out = (float*)d_out;

    dim3 grid(N_ / QB, B_ * H_);
    g2attn_kernel<<<grid, THREADS, 0, stream>>>(o, mix, alpha, beta, out);
}

// Round 2
// 128.006 us; speedup vs baseline: 1.1520x; 1.1520x over previous
//
#include <hip/hip_runtime.h>
#include <math.h>

#define B_ 2
#define N_ 2048
#define H_ 16

constexpr int QB      = 256;          // queries per block
constexpr int QPT     = 2;            // queries per thread
constexpr int QT      = QB / QPT;     // 128 query-threads
constexpr int KSPLIT  = 8;            // key-split per query
constexpr int THREADS = QT * KSPLIT;  // 1024
constexpr int KCHUNK  = N_ / KSPLIT;  // 256

#if __has_builtin(__builtin_amdgcn_exp2f)
__device__ __forceinline__ float ex2(float x) { return __builtin_amdgcn_exp2f(x); }
#else
__device__ __forceinline__ float ex2(float x) {
    float r; asm("v_exp_f32 %0, %1" : "=v"(r) : "v"(x)); return r;
}
#endif

__global__ __launch_bounds__(THREADS, 1)
void g2attn_kernel(const float* __restrict__ o,
                   const float* __restrict__ mix,
                   const float* __restrict__ alpha,
                   const float* __restrict__ beta,
                   float* __restrict__ out)
{
    // all keys for this (b,h): 2048 x 8 floats = 64 KiB (reused for partials)
    __shared__ float skv[N_][8];

    const int bh = blockIdx.y;            // 0..31
    const int b  = bh >> 4;
    const int h  = bh & (H_ - 1);
    const int n0 = blockIdx.x * QB;

    const float* obase = o + ((size_t)b * N_ * (H_ * 8)) + h * 8;

    // cooperative stage: one row (2 x float4) per step
    for (int i = threadIdx.x; i < N_; i += THREADS) {
        const float* src = obase + (size_t)i * (H_ * 8);
        const float4 a = *(const float4*)src;
        const float4 c = *(const float4*)(src + 4);
        *(float4*)&skv[i][0] = a;
        *(float4*)&skv[i][4] = c;
    }
    __syncthreads();

    const int qt = threadIdx.x & (QT - 1);
    const int ks = threadIdx.x / QT;      // 0..7

    // head constants: w_k = softmax(mix[h])[0]; fold scale & log2(e) into q
    const float m0 = mix[h * 2 + 0], m1 = mix[h * 2 + 1];
    const float wk = 1.0f / (1.0f + __expf(m1 - m0));
    const float c2 = wk * 0.5453442457918520f;   // log2(e)/sqrt(7)

    float realv[QPT], qf[QPT][7], qs[QPT][7];
    #pragma unroll
    for (int u = 0; u < QPT; ++u) {
        const int qrow = n0 + qt + u * QT;
        const float4 a = *(const float4*)&skv[qrow][0];
        const float4 c = *(const float4*)&skv[qrow][4];
        realv[u] = a.x;
        qf[u][0] = a.y; qf[u][1] = a.z; qf[u][2] = a.w;
        qf[u][3] = c.x; qf[u][4] = c.y; qf[u][5] = c.z; qf[u][6] = c.w;
        #pragma unroll
        for (int d = 0; d < 7; ++d) qs[u][d] = qf[u][d] * c2;
    }

    float l[QPT], ac[QPT][7];
    #pragma unroll
    for (int u = 0; u < QPT; ++u) {
        l[u] = 0.f;
        #pragma unroll
        for (int d = 0; d < 7; ++d) ac[u][d] = 0.f;
    }

    // no-max softmax accumulation (scores bounded -> fp32 safe, raw v_exp ok)
    const int t0 = ks * KCHUNK;
    #pragma unroll 8
    for (int t = t0; t < t0 + KCHUNK; ++t) {
        const float4 kA = *(const float4*)&skv[t][0];
        const float4 kB = *(const float4*)&skv[t][4];
        #pragma unroll
        for (int u = 0; u < QPT; ++u) {
            float s =  qs[u][0] * kA.y;
            s = fmaf(qs[u][1], kA.z, s);
            s = fmaf(qs[u][2], kA.w, s);
            s = fmaf(qs[u][3], kB.x, s);
            s = fmaf(qs[u][4], kB.y, s);
            s = fmaf(qs[u][5], kB.z, s);
            s = fmaf(qs[u][6], kB.w, s);
            const float p = ex2(s);
            l[u] += p;
            ac[u][0] = fmaf(p, kA.y, ac[u][0]);
            ac[u][1] = fmaf(p, kA.z, ac[u][1]);
            ac[u][2] = fmaf(p, kA.w, ac[u][2]);
            ac[u][3] = fmaf(p, kB.x, ac[u][3]);
            ac[u][4] = fmaf(p, kB.y, ac[u][4]);
            ac[u][5] = fmaf(p, kB.z, ac[u][5]);
            ac[u][6] = fmaf(p, kB.w, ac[u][6]);
        }
    }

    // merge KSPLIT partials through LDS (reuse skv; stride 9 -> conflict-free)
    __syncthreads();
    float* part = &skv[0][0];   // need 7*256*9 = 16128 floats <= 16384 available
    if (ks > 0) {
        #pragma unroll
        for (int u = 0; u < QPT; ++u) {
            float* p = part + ((size_t)((ks - 1) * QB) + u * QT + qt) * 9;
            p[0] = l[u];
            #pragma unroll
            for (int d = 0; d < 7; ++d) p[1 + d] = ac[u][d];
        }
    }
    __syncthreads();
    if (ks != 0) return;

    const float sa = 1.0f / (1.0f + __expf(-alpha[h]));
    const float tb = tanhf(beta[h]);

    #pragma unroll
    for (int u = 0; u < QPT; ++u) {
        #pragma unroll
        for (int s2 = 0; s2 < KSPLIT - 1; ++s2) {
            const float* p = part + ((size_t)(s2 * QB) + u * QT + qt) * 9;
            l[u] += p[0];
            #pragma unroll
            for (int d = 0; d < 7; ++d) ac[u][d] += p[1 + d];
        }
        const float invl = 1.0f / l[u];
        // y_v == k_pooled (k ≡ v; oct_cross(k,k) == 0)
        float ya[7], xa[7] = {0.f, 0.f, 0.f, 0.f, 0.f, 0.f, 0.f};
        #pragma unroll
        for (int d = 0; d < 7; ++d) ya[d] = ac[u][d] * invl;

        const int TR[7][3] = {{0,1,2},{0,3,4},{0,6,5},{1,3,5},{1,4,6},{2,3,6},{2,5,4}};
        #pragma unroll
        for (int t = 0; t < 7; ++t) {
            const int i = TR[t][0], j = TR[t][1], k = TR[t][2];
            xa[k] += qf[u][i] * ya[j] - qf[u][j] * ya[i];
            xa[i] += qf[u][j] * ya[k] - qf[u][k] * ya[j];
            xa[j] += qf[u][k] * ya[i] - qf[u][i] * ya[k];
        }

        float im[7];
        float nsq = realv[u] * realv[u];
        #pragma unroll
        for (int d = 0; d < 7; ++d) {
            im[d] = sa * ya[d] + tb * xa[d];
            nsq = fmaf(im[d], im[d], nsq);
        }
        const float inv = 1.0f / fmaxf(sqrtf(nsq), 1e-12f);

        const int qrow = n0 + qt + u * QT;
        float* dst = out + ((size_t)(b * N_ + qrow) * H_ + h) * 8;
        float4 oA = { realv[u] * inv, im[0] * inv, im[1] * inv, im[2] * inv };
        float4 oB = { im[3] * inv, im[4] * inv, im[5] * inv, im[6] * inv };
        *(float4*)dst       = oA;
        *(float4*)(dst + 4) = oB;
    }
}

extern "C" void kernel_launch(void* const* d_in, const int* in_sizes, int n_in,
                              void* d_out, int out_size, void* d_ws, size_t ws_size,
                              hipStream_t stream) {
    const float* o     = (const float*)d_in[0];
    const float* mix   = (const float*)d_in[1];
    const float* alpha = (const float*)d_in[2];
    const float* beta  = (const float*)d_in[3];
    float* out = (float*)d_out;

    dim3 grid(N_ / QB, B_ * H_);
    g2attn_kernel<<<grid, THREADS, 0, stream>>>(o, mix, alpha, beta, out);
}

// Round 3
// 122.324 us; speedup vs baseline: 1.2055x; 1.0464x over previous
//
#include <hip/hip_runtime.h>
#include <math.h>

#define B_ 2
#define N_ 2048
#define H_ 16

constexpr int QB      = 256;          // queries per block
constexpr int QPT     = 4;            // queries per thread
constexpr int QT      = QB / QPT;     // 64 query-threads (= 1 wave)
constexpr int KSPLIT  = 16;           // key-split per query (= wave id)
constexpr int THREADS = QT * KSPLIT;  // 1024
constexpr int KCHUNK  = N_ / KSPLIT;  // 128

#if __has_builtin(__builtin_amdgcn_exp2f)
__device__ __forceinline__ float ex2(float x) { return __builtin_amdgcn_exp2f(x); }
#else
__device__ __forceinline__ float ex2(float x) {
    float r; asm("v_exp_f32 %0, %1" : "=v"(r) : "v"(x)); return r;
}
#endif

__global__ __launch_bounds__(THREADS, 1)
void g2attn_kernel(const float* __restrict__ o,
                   const float* __restrict__ mix,
                   const float* __restrict__ alpha,
                   const float* __restrict__ beta,
                   float* __restrict__ out)
{
    // all keys for this (b,h): 2048 x 8 floats = 64 KiB (reused for merge)
    __shared__ float skv[N_][8];

    const int bh = blockIdx.y;            // 0..31
    const int b  = bh >> 4;
    const int h  = bh & (H_ - 1);
    const int n0 = blockIdx.x * QB;

    const float* obase = o + ((size_t)b * N_ * (H_ * 8)) + h * 8;

    // cooperative stage
    for (int i = threadIdx.x; i < N_; i += THREADS) {
        const float* src = obase + (size_t)i * (H_ * 8);
        const float4 a = *(const float4*)src;
        const float4 c = *(const float4*)(src + 4);
        *(float4*)&skv[i][0] = a;
        *(float4*)&skv[i][4] = c;
    }
    __syncthreads();

    const int qt = threadIdx.x & (QT - 1);   // lane within wave
    const int ks = threadIdx.x >> 6;         // wave id = key split, 0..15

    // head constants: w_k = softmax(mix[h])[0]; fold scale & log2(e) into q
    const float m0 = mix[h * 2 + 0], m1 = mix[h * 2 + 1];
    const float wk = 1.0f / (1.0f + __expf(m1 - m0));
    const float c2 = wk * 0.5453442457918520f;   // log2(e)/sqrt(7)

    float realv[QPT], qs[QPT][7];
    #pragma unroll
    for (int u = 0; u < QPT; ++u) {
        const int qrow = n0 + u * QT + qt;
        const float4 a = *(const float4*)&skv[qrow][0];
        const float4 c = *(const float4*)&skv[qrow][4];
        realv[u] = a.x;
        qs[u][0] = a.y * c2; qs[u][1] = a.z * c2; qs[u][2] = a.w * c2;
        qs[u][3] = c.x * c2; qs[u][4] = c.y * c2; qs[u][5] = c.z * c2;
        qs[u][6] = c.w * c2;
    }

    float l[QPT], ac[QPT][7];
    #pragma unroll
    for (int u = 0; u < QPT; ++u) {
        l[u] = 0.f;
        #pragma unroll
        for (int d = 0; d < 7; ++d) ac[u][d] = 0.f;
    }

    // no-max softmax accumulation (scores bounded -> fp32 safe, raw v_exp ok)
    const int t0 = ks * KCHUNK;
    #pragma unroll 4
    for (int t = t0; t < t0 + KCHUNK; ++t) {
        const float4 kA = *(const float4*)&skv[t][0];   // wave-uniform broadcast
        const float4 kB = *(const float4*)&skv[t][4];
        #pragma unroll
        for (int u = 0; u < QPT; ++u) {
            float s =  qs[u][0] * kA.y;
            s = fmaf(qs[u][1], kA.z, s);
            s = fmaf(qs[u][2], kA.w, s);
            s = fmaf(qs[u][3], kB.x, s);
            s = fmaf(qs[u][4], kB.y, s);
            s = fmaf(qs[u][5], kB.z, s);
            s = fmaf(qs[u][6], kB.w, s);
            const float p = ex2(s);
            l[u] += p;
            ac[u][0] = fmaf(p, kA.y, ac[u][0]);
            ac[u][1] = fmaf(p, kA.z, ac[u][1]);
            ac[u][2] = fmaf(p, kA.w, ac[u][2]);
            ac[u][3] = fmaf(p, kB.x, ac[u][3]);
            ac[u][4] = fmaf(p, kB.y, ac[u][4]);
            ac[u][5] = fmaf(p, kB.z, ac[u][5]);
            ac[u][6] = fmaf(p, kB.w, ac[u][6]);
        }
    }

    // hierarchical KSPLIT merge through skv (log2(16)=4 rounds; round A = 64 KB)
    float* part = &skv[0][0];
    #pragma unroll
    for (int half = KSPLIT / 2; half >= 1; half >>= 1) {
        __syncthreads();
        if (ks >= half && ks < 2 * half) {
            #pragma unroll
            for (int u = 0; u < QPT; ++u) {
                float* p = part + ((size_t)(((ks - half) * QPT + u) * QT + qt)) * 8;
                float4 w0 = { l[u],     ac[u][0], ac[u][1], ac[u][2] };
                float4 w1 = { ac[u][3], ac[u][4], ac[u][5], ac[u][6] };
                *(float4*)(p)     = w0;
                *(float4*)(p + 4) = w1;
            }
        }
        __syncthreads();
        if (ks < half) {
            #pragma unroll
            for (int u = 0; u < QPT; ++u) {
                const float* p = part + ((size_t)((ks * QPT + u) * QT + qt)) * 8;
                const float4 r0 = *(const float4*)(p);
                const float4 r1 = *(const float4*)(p + 4);
                l[u]     += r0.x;
                ac[u][0] += r0.y; ac[u][1] += r0.z; ac[u][2] += r0.w;
                ac[u][3] += r1.x; ac[u][4] += r1.y; ac[u][5] += r1.z;
                ac[u][6] += r1.w;
            }
        }
    }
    if (ks != 0) return;

    const float sa = 1.0f / (1.0f + __expf(-alpha[h]));
    const float tb = tanhf(beta[h]);
    const float inv_c2 = 1.0f / c2;

    #pragma unroll
    for (int u = 0; u < QPT; ++u) {
        const float invl = 1.0f / l[u];
        // y_v == k_pooled (k ≡ v; oct_cross(k,k) == 0)
        float ya[7], qf[7], xa[7] = {0.f, 0.f, 0.f, 0.f, 0.f, 0.f, 0.f};
        #pragma unroll
        for (int d = 0; d < 7; ++d) {
            ya[d] = ac[u][d] * invl;
            qf[d] = qs[u][d] * inv_c2;
        }

        const int TR[7][3] = {{0,1,2},{0,3,4},{0,6,5},{1,3,5},{1,4,6},{2,3,6},{2,5,4}};
        #pragma unroll
        for (int t = 0; t < 7; ++t) {
            const int i = TR[t][0], j = TR[t][1], k = TR[t][2];
            xa[k] += qf[i] * ya[j] - qf[j] * ya[i];
            xa[i] += qf[j] * ya[k] - qf[k] * ya[j];
            xa[j] += qf[k] * ya[i] - qf[i] * ya[k];
        }

        float im[7];
        float nsq = realv[u] * realv[u];
        #pragma unroll
        for (int d = 0; d < 7; ++d) {
            im[d] = sa * ya[d] + tb * xa[d];
            nsq = fmaf(im[d], im[d], nsq);
        }
        const float inv = 1.0f / fmaxf(sqrtf(nsq), 1e-12f);

        const int qrow = n0 + u * QT + qt;
        float* dst = out + ((size_t)(b * N_ + qrow) * H_ + h) * 8;
        float4 oA = { realv[u] * inv, im[0] * inv, im[1] * inv, im[2] * inv };
        float4 oB = { im[3] * inv, im[4] * inv, im[5] * inv, im[6] * inv };
        *(float4*)dst       = oA;
        *(float4*)(dst + 4) = oB;
    }
}

extern "C" void kernel_launch(void* const* d_in, const int* in_sizes, int n_in,
                              void* d_out, int out_size, void* d_ws, size_t ws_size,
                              hipStream_t stream) {
    const float* o     = (const float*)d_in[0];
    const float* mix   = (const float*)d_in[1];
    const float* alpha = (const float*)d_in[2];
    const float* beta  = (const float*)d_in[3];
    float* out = (float*)d_out;

    dim3 grid(N_ / QB, B_ * H_);
    g2attn_kernel<<<grid, THREADS, 0, stream>>>(o, mix, alpha, beta, out);
}

// Round 5
// 83.408 us; speedup vs baseline: 1.7680x; 1.4666x over previous
//
#include <hip/hip_runtime.h>
#include <math.h>

#define B_ 2
#define N_ 2048
#define H_ 16

typedef _Float16 f16x4 __attribute__((ext_vector_type(4)));
typedef float    f32x4 __attribute__((ext_vector_type(4)));

constexpr int THREADS = 512;      // 8 waves
constexpr int NPAIR   = N_ / 32;  // 64 pairs of 16-key blocks
constexpr int QTPB    = 16;       // 16 q-tiles (of 16) per block = 256 q

#if __has_builtin(__builtin_amdgcn_exp2f)
__device__ __forceinline__ float ex2(float x) { return __builtin_amdgcn_exp2f(x); }
#else
__device__ __forceinline__ float ex2(float x) { float r; asm("v_exp_f32 %0, %1" : "=v"(r) : "v"(x)); return r; }
#endif

__global__ __launch_bounds__(THREADS, 1)
void g2attn_mfma(const float* __restrict__ o, const float* __restrict__ mix,
                 const float* __restrict__ alpha, const float* __restrict__ beta,
                 float* __restrict__ out)
{
    // Fragment-ordered f16 LDS: lane-linear so reads are wide & regular.
    __shared__ _Float16 sQ[NPAIR * 32 * 8];  // Q frags: raw imag dims, dim7 = +1
    __shared__ _Float16 sK[NPAIR * 32 * 8];  // K frags: c2-scaled, dim7 = -12 (bias)
    __shared__ _Float16 sP[NPAIR * 28 * 8];  // KV^T frags for PV (cols 0..6)
    __shared__ float    sE[8 * 16 * 8];      // per-wave epilogue gather

    const int bh = blockIdx.y, b = bh >> 4, h = bh & (H_ - 1);
    const int tid = threadIdx.x;
    const float* obase = o + ((size_t)b * N_ * (H_ * 8)) + h * 8;

    const float m0 = mix[h * 2 + 0], m1 = mix[h * 2 + 1];
    const float wk = 1.0f / (1.0f + __expf(m1 - m0));
    const float c2 = wk * 0.5453442457918520f;   // log2(e)/sqrt(7) * w_k

    // ---- build fragment buffers (k == v == q rows; k_cross_v == 0) ----
    for (int i = tid; i < N_; i += THREADS) {
        const float* src = obase + (size_t)i * (H_ * 8);
        const float4 va = *(const float4*)src;
        const float4 vb = *(const float4*)(src + 4);
        const float hd[7] = {va.y, va.z, va.w, vb.x, vb.y, vb.z, vb.w};
        const int pair = i >> 5, sub = (i >> 4) & 1, r = i & 15;
        f16x4 qlo = {(_Float16)hd[0], (_Float16)hd[1], (_Float16)hd[2], (_Float16)hd[3]};
        f16x4 qhi = {(_Float16)hd[4], (_Float16)hd[5], (_Float16)hd[6], (_Float16)1.0f};
        f16x4 klo = {(_Float16)(c2*hd[0]), (_Float16)(c2*hd[1]), (_Float16)(c2*hd[2]), (_Float16)(c2*hd[3])};
        f16x4 khi = {(_Float16)(c2*hd[4]), (_Float16)(c2*hd[5]), (_Float16)(c2*hd[6]), (_Float16)(-12.0f)};
        *(f16x4*)&sQ[((pair*32 + r)*8) + sub*4]      = qlo;
        *(f16x4*)&sQ[((pair*32 + 16 + r)*8) + sub*4] = qhi;
        *(f16x4*)&sK[((pair*32 + r)*8) + sub*4]      = klo;
        *(f16x4*)&sK[((pair*32 + 16 + r)*8) + sub*4] = khi;
        const int gw = r >> 2, jw = r & 3;
        #pragma unroll
        for (int c = 0; c < 7; ++c)
            sP[(pair*28 + gw*7 + c)*8 + sub*4 + jw] = (_Float16)hd[c];
    }
    __syncthreads();

    const int lane = tid & 63, wave = tid >> 6;
    const int cc = lane & 15, g = lane >> 4;

    const f16x4 z4   = {(_Float16)0.f, (_Float16)0.f, (_Float16)0.f, (_Float16)0.f};
    const f16x4 one4 = {(_Float16)1.f, (_Float16)1.f, (_Float16)1.f, (_Float16)1.f};
    const f32x4 zf   = {0.f, 0.f, 0.f, 0.f};

    // this wave's two q-tiles (consecutive -> same pair slot)
    const int t0 = blockIdx.x * QTPB + wave * 2;
    f16x4 qb0 = z4, qb1 = z4;
    if (lane < 32) {
        qb0 = *(const f16x4*)&sQ[((t0 >> 1)*32 + lane)*8 + 0];
        qb1 = *(const f16x4*)&sQ[((t0 >> 1)*32 + lane)*8 + 4];
    }

    auto loadPair = [&](int p, f16x4& a0, f16x4& a1, f16x4& b0, f16x4& b1) {
        if (lane < 32) {
            const f16x4* s = (const f16x4*)&sK[(p*32 + lane)*8];
            a0 = s[0]; a1 = s[1];
        } else { a0 = z4; a1 = z4; }
        if (cc < 7) {
            const f16x4* s = (const f16x4*)&sP[(p*28 + g*7 + cc)*8];
            b0 = s[0]; b1 = s[1];
        } else if (cc == 7) { b0 = one4; b1 = one4; }
        else { b0 = z4; b1 = z4; }
    };

    f32x4 acc0 = zf, acc1 = zf;
    f16x4 ka0, ka1, pa0, pa1;
    loadPair(0, ka0, ka1, pa0, pa1);

    for (int p = 0; p < NPAIR; ++p) {
        f16x4 nk0 = z4, nk1 = z4, np0 = z4, np1 = z4;
        if (p + 1 < NPAIR) loadPair(p + 1, nk0, nk1, np0, np1);

        // S^T tiles: s = c2*dot(q,k) - 12 (scale+bias folded into frags)
        f32x4 s0 = __builtin_amdgcn_mfma_f32_16x16x16f16(ka0, qb0, zf, 0, 0, 0);
        f32x4 s1 = __builtin_amdgcn_mfma_f32_16x16x16f16(ka0, qb1, zf, 0, 0, 0);
        f32x4 s2 = __builtin_amdgcn_mfma_f32_16x16x16f16(ka1, qb0, zf, 0, 0, 0);
        f32x4 s3 = __builtin_amdgcn_mfma_f32_16x16x16f16(ka1, qb1, zf, 0, 0, 0);

        f16x4 pb0, pb1, pb2, pb3;
        #define MKPB(S, PB) { \
            float e0 = ex2(S[0]), e1 = ex2(S[1]), e2 = ex2(S[2]), e3 = ex2(S[3]); \
            auto lo = __builtin_amdgcn_cvt_pkrtz(e0, e1); \
            auto hi = __builtin_amdgcn_cvt_pkrtz(e2, e3); \
            PB[0] = (_Float16)lo[0]; PB[1] = (_Float16)lo[1]; \
            PB[2] = (_Float16)hi[0]; PB[3] = (_Float16)hi[1]; }
        MKPB(s0, pb0) MKPB(s1, pb1) MKPB(s2, pb2) MKPB(s3, pb3)
        #undef MKPB

        // O^T accumulate: C-frag P^T layout == B-operand layout (no shuffles)
        acc0 = __builtin_amdgcn_mfma_f32_16x16x16f16(pa0, pb0, acc0, 0, 0, 0);
        acc1 = __builtin_amdgcn_mfma_f32_16x16x16f16(pa0, pb1, acc1, 0, 0, 0);
        acc0 = __builtin_amdgcn_mfma_f32_16x16x16f16(pa1, pb2, acc0, 0, 0, 0);
        acc1 = __builtin_amdgcn_mfma_f32_16x16x16f16(pa1, pb3, acc1, 0, 0, 0);

        ka0 = nk0; ka1 = nk1; pa0 = np0; pa1 = np1;
    }

    // ---- epilogue: rows c=0..6 are sum(p*k), row c=7 is l = sum(p) ----
    const float sa = 1.0f / (1.0f + __expf(-alpha[h]));
    const float tb = tanhf(beta[h]);

    #pragma unroll
    for (int which = 0; which < 2; ++which) {
        __syncthreads();
        const f32x4 a = which ? acc1 : acc0;
        if (lane < 32) {
            #pragma unroll
            for (int r = 0; r < 4; ++r)
                sE[(wave*16 + cc)*8 + g*4 + r] = a[r];
        }
        __syncthreads();
        if (lane < 16) {
            const float* e = &sE[(wave*16 + lane)*8];
            const float invl = 1.0f / e[7];
            float ya[7];
            #pragma unroll
            for (int d = 0; d < 7; ++d) ya[d] = e[d] * invl;

            const int q = (t0 + which)*16 + lane;
            const float* src = obase + (size_t)q * (H_ * 8);
            const float4 va = *(const float4*)src;
            const float4 vb = *(const float4*)(src + 4);
            const float realv = va.x;
            const float qf[7] = {va.y, va.z, va.w, vb.x, vb.y, vb.z, vb.w};

            float xa[7] = {0.f, 0.f, 0.f, 0.f, 0.f, 0.f, 0.f};
            const int TR[7][3] = {{0,1,2},{0,3,4},{0,6,5},{1,3,5},{1,4,6},{2,3,6},{2,5,4}};
            #pragma unroll
            for (int t = 0; t < 7; ++t) {
                const int i = TR[t][0], j = TR[t][1], k = TR[t][2];
                xa[k] += qf[i]*ya[j] - qf[j]*ya[i];
                xa[i] += qf[j]*ya[k] - qf[k]*ya[j];
                xa[j] += qf[k]*ya[i] - qf[i]*ya[k];
            }

            float im[7], nsq = realv * realv;
            #pragma unroll
            for (int d = 0; d < 7; ++d) {
                im[d] = sa*ya[d] + tb*xa[d];
                nsq = fmaf(im[d], im[d], nsq);
            }
            const float inv = 1.0f / fmaxf(sqrtf(nsq), 1e-12f);

            float* dst = out + ((size_t)(b*N_ + q)*H_ + h)*8;
            float4 oA = {realv*inv, im[0]*inv, im[1]*inv, im[2]*inv};
            float4 oB = {im[3]*inv, im[4]*inv, im[5]*inv, im[6]*inv};
            *(float4*)dst       = oA;
            *(float4*)(dst + 4) = oB;
        }
    }
}

extern "C" void kernel_launch(void* const* d_in, const int* in_sizes, int n_in,
                              void* d_out, int out_size, void* d_ws, size_t ws_size,
                              hipStream_t stream) {
    const float* o     = (const float*)d_in[0];
    const float* mix   = (const float*)d_in[1];
    const float* alpha = (const float*)d_in[2];
    const float* beta  = (const float*)d_in[3];
    float* out = (float*)d_out;

    dim3 grid(N_ / (QTPB * 16), B_ * H_);   // 8 x 32 = 256 blocks
    g2attn_mfma<<<grid, THREADS, 0, stream>>>(o, mix, alpha, beta, out);
}